// Round 6
// baseline (148.900 us; speedup 1.0000x reference)
//
#include <hip/hip_runtime.h>

// SkipGram negative-sampling loss. B=32768, K=16, D=128, fp32 inputs.
// Round 13: DELETE the fp8 table + convert_con kernel; gather con_emb fp32
// directly.
//   Model (fits R7..R12): main is REQUEST-RATE bound — 18 wave-gathers per b
//   x ~26 cy/request per CU = ~25 us, independent of bytes/request (128 B fp8
//   vs 512 B fp32 both below the ~1 KB/request port ceiling). The fp8 table
//   never sped up main; it only cost an 11-us BW-floor conversion kernel
//   (64 MB) every iteration. Direct fp32 removes that kernel outright.
//   Risk carried: con refs now L3-serviced at 512 B (per-XCD L2 was already
//   too small for the fp8 table; FETCH 39MB < 88MB requested proved L3
//   absorption). Accuracy strictly improves (exact fp32).
// Body: persistent single-batch grid (2048 blocks, 8/CU), 1 b per iteration
// x 4 iterations, DPP xor1/xor2 reduce, no block barrier.

constexpr int Bn = 32768;
constexpr int Kn = 16;
constexpr int WPB = 4;                    // waves per block (256 threads)
constexpr int NBLK = 2048;                // 8 blocks/CU x 256 CU, single batch
constexpr int NWAVE = NBLK * WPB;         // 8192 resident waves
constexpr int NITER = Bn / NWAVE;         // 4 b per wave
constexpr int VOCAB = 100000;
constexpr int DIM = 128;

typedef float f32x2 __attribute__((ext_vector_type(2)));

// DPP quad_perm controls: xor-1 = (1,0,3,2) = 0xB1, xor-2 = (2,3,0,1) = 0x4E.
constexpr int XOR1 = 0xB1;
constexpr int XOR2 = 0x4E;

__device__ __forceinline__ float log_sigmoid_fast(float x) {
  // min(x,0) - log(1 + exp(-|x|)); log arg in (1,2] -> hw v_log_f32 accurate
  return fminf(x, 0.0f) - __logf(1.0f + __expf(-fabsf(x)));
}

// Fetch partner-lane value at xor distance 1 or 2 via DPP (VALU, no LDS).
template<int CTRL>
__device__ __forceinline__ float dpp_xor(float x) {
  int r = __builtin_amdgcn_update_dpp(0, __float_as_int(x), CTRL, 0xF, 0xF, true);
  return __int_as_float(r);
}

// Multi-value butterfly step via __shfl_xor (LDS crossbar) — masks >= 4.
template<int M, int C>
__device__ __forceinline__ void tree_step(float* v, int lane) {
  const bool hi = (lane & M) != 0;
  const int H = C / 2;
#pragma unroll
  for (int j = 0; j < H; ++j) {
    float send = hi ? v[j] : v[j + H];
    float keep = hi ? v[j + H] : v[j];
    v[j] = keep + __shfl_xor(send, M, 64);
  }
}

// Multi-value butterfly step via DPP quad_perm — masks 1 and 2.
template<int M, int CTRL, int C>
__device__ __forceinline__ void tree_step_dpp(float* v, int lane) {
  const bool hi = (lane & M) != 0;
  const int H = C / 2;
#pragma unroll
  for (int j = 0; j < H; ++j) {
    float send = hi ? v[j] : v[j + H];
    float keep = hi ? v[j + H] : v[j];
    v[j] = keep + dpp_xor<CTRL>(send);
  }
}

__global__ __launch_bounds__(256, 8) void skipgram_main(
    const int* __restrict__ centrals,
    const int* __restrict__ pos_ctx,
    const int* __restrict__ neg_ctx,
    const float* __restrict__ word_emb,
    const float* __restrict__ con_emb,
    float* __restrict__ b_sums)
{
  const int lane = threadIdx.x & 63;
  const int wid = threadIdx.x >> 6;
  const int gw = blockIdx.x * WPB + wid;      // global wave id, 0..8191

  const float2* __restrict__ W = reinterpret_cast<const float2*>(word_emb);
  const float2* __restrict__ C = reinterpret_cast<const float2*>(con_emb);

  for (int t = 0; t < NITER; ++t) {
    // Contiguous b per wave: iter t+1's 64-B neg_ctx row shares scalar-cache
    // lines with iter t's -> s_load hits.
    int b = gw * NITER + t;
    b = __builtin_amdgcn_readfirstlane(b);    // wave-uniform -> s_load path

    // Scalar index loads (wave-uniform addresses -> s_load).
    const int cw = centrals[b];
    const int pc = pos_ctx[b];
    int ni[Kn];
#pragma unroll
    for (int k = 0; k < Kn; ++k) ni[k] = neg_ctx[b * Kn + k];

    // Issue all 18 row gathers back-to-back. Full-wave contiguous rows:
    // 512 B fp32 (float2/lane) each — the proven-fast request shape.
    const float2 wv = W[(size_t)cw * 64 + lane];
    const float2 cv = C[(size_t)pc * 64 + lane];
    float2 nv[Kn];
#pragma unroll
    for (int k = 0; k < Kn; ++k) nv[k] = C[(size_t)ni[k] * 64 + lane];

    // Per-lane partial dots (independent chains, ILP).
    float v[Kn];
#pragma unroll
    for (int k = 0; k < Kn; ++k)
      v[k] = fmaf(wv.x, nv[k].x, wv.y * nv[k].y);

    // Butterfly tree: xor-1/xor-2 via DPP (VALU), xor>=4 via shuffle.
    tree_step_dpp<1, XOR1, 16>(v, lane);
    tree_step_dpp<2, XOR2,  8>(v, lane);
    tree_step<4, 4>(v, lane);
    tree_step<8, 2>(v, lane);
    float s = v[0];
    s += __shfl_xor(s, 16, 64);
    s += __shfl_xor(s, 32, 64);

    // Sum log-sigmoids of the 16 distinct scores.
    float nls = log_sigmoid_fast(-s);
    nls += dpp_xor<XOR1>(nls);
    nls += dpp_xor<XOR2>(nls);
    nls += __shfl_xor(nls, 4, 64);
    nls += __shfl_xor(nls, 8, 64);          // neg_loss total (all lanes)

    // Positive score.
    float pp = fmaf(wv.x, cv.x, wv.y * cv.y);
    pp += dpp_xor<XOR1>(pp);
    pp += dpp_xor<XOR2>(pp);
    pp += __shfl_xor(pp,  4, 64);
    pp += __shfl_xor(pp,  8, 64);
    pp += __shfl_xor(pp, 16, 64);
    pp += __shfl_xor(pp, 32, 64);

    const float acc = log_sigmoid_fast(pp) + nls;

    // Per-wave store: no smem, no barrier — waves retire independently.
    if (lane == 0) b_sums[b] = acc;
  }
}

__global__ __launch_bounds__(256) void skipgram_reduce(
    const float* __restrict__ b_sums, float* __restrict__ out)
{
  float s = 0.0f;
#pragma unroll
  for (int i = 0; i < Bn / 256; ++i) s += b_sums[i * 256 + threadIdx.x];
  s += __shfl_xor(s,  1, 64);
  s += __shfl_xor(s,  2, 64);
  s += __shfl_xor(s,  4, 64);
  s += __shfl_xor(s,  8, 64);
  s += __shfl_xor(s, 16, 64);
  s += __shfl_xor(s, 32, 64);
  __shared__ float smem[4];
  const int lane = threadIdx.x & 63;
  if (lane == 0) smem[threadIdx.x >> 6] = s;
  __syncthreads();
  if (threadIdx.x == 0) {
    float t = (smem[0] + smem[1]) + (smem[2] + smem[3]);
    out[0] = -t * (1.0f / (float)Bn);     // loss = -mean(pos_loss + neg_loss)
  }
}

extern "C" void kernel_launch(void* const* d_in, const int* in_sizes, int n_in,
                              void* d_out, int out_size, void* d_ws, size_t ws_size,
                              hipStream_t stream) {
  const int*   centrals = (const int*)d_in[0];
  const int*   pos_ctx  = (const int*)d_in[1];
  const int*   neg_ctx  = (const int*)d_in[2];
  const float* word_emb = (const float*)d_in[3];
  const float* con_emb  = (const float*)d_in[4];
  float*       out      = (float*)d_out;

  float* b_sums = (float*)d_ws;                 // 128 KB per-b partials

  // 1) gathers + dots + log-sigmoid -> per-b partials (persistent grid).
  skipgram_main<<<NBLK, 256, 0, stream>>>(centrals, pos_ctx, neg_ctx,
                                          word_emb, con_emb, b_sums);

  // 2) final mean.
  skipgram_reduce<<<1, 256, 0, stream>>>(b_sums, out);
}

// Round 7
// 135.793 us; speedup vs baseline: 1.0965x; 1.0965x over previous
//
#include <hip/hip_runtime.h>

// SkipGram negative-sampling loss. B=32768, K=16, D=128, fp32 inputs.
// Round 14: REVERT to the verified-best R12 configuration (136.2 us).
// R13 (fp32-direct, no convert) measured WORSE: main 25 -> 44 us because
// fp32 con rows (512 B) blow per-XCD L2 (FETCH 39 -> 140 MB) and the L3
// random-line service rate (~3.2 TB/s) makes main fabric-bound. The fp8
// table keeps main's fetch at 39 MB (~12 us fabric, hidden under the 25-us
// request floor) at the cost of an 11-us BW-roofline convert kernel.
// Final model (fits R7-R13):
//   main  = max(18 req/b x ~26 cy/req  -> ~25 us  [request-rate bound],
//               fetch_bytes / 3.2 TB/s -> ~12 us with fp8)
//   convert = 64 MB @ HBM roofline     -> ~11 us
//   reduce                              -> ~2 us
//   + ~98 us fixed harness resets (256 MB ws poison + input restores).
// Structure: persistent single-batch grid (2048 blocks = 8/CU), 2 b per
// iteration x 2 iterations, DPP xor1/xor2 reduce, no block barrier.

constexpr int Bn = 32768;
constexpr int Kn = 16;
constexpr int WPB = 4;                    // waves per block (256 threads)
constexpr int BPW = 2;                    // b's per loop iteration
constexpr int NBLK = 2048;                // 8 blocks/CU x 256 CU, single batch
constexpr int NWAVE = NBLK * WPB;         // 8192 resident waves
constexpr int NITER = Bn / (NWAVE * BPW); // 2 iterations per wave
constexpr int NSUM = NWAVE * NITER;       // 16384 per-wave-iter partials
constexpr int VOCAB = 100000;
constexpr int DIM = 128;
constexpr size_t CONV_OFF = 65536;        // byte offset of fp8 table in d_ws
constexpr float SCALE = 256.0f;           // fp32 -> e4m3 pre-scale
constexpr float INV_SCALE = 1.0f / 256.0f;

typedef float f32x2 __attribute__((ext_vector_type(2)));

// DPP quad_perm controls: xor-1 = (1,0,3,2) = 0xB1, xor-2 = (2,3,0,1) = 0x4E.
constexpr int XOR1 = 0xB1;
constexpr int XOR2 = 0x4E;

__device__ __forceinline__ float log_sigmoid_fast(float x) {
  // min(x,0) - log(1 + exp(-|x|)); log arg in (1,2] -> hw v_log_f32 accurate
  return fminf(x, 0.0f) - __logf(1.0f + __expf(-fabsf(x)));
}

// Fetch partner-lane value at xor distance 1 or 2 via DPP (VALU, no LDS).
template<int CTRL>
__device__ __forceinline__ float dpp_xor(float x) {
  int r = __builtin_amdgcn_update_dpp(0, __float_as_int(x), CTRL, 0xF, 0xF, true);
  return __int_as_float(r);
}

// Multi-value butterfly step via __shfl_xor (LDS crossbar) — masks >= 4.
template<int M, int C>
__device__ __forceinline__ void tree_step(float* v, int lane) {
  const bool hi = (lane & M) != 0;
  const int H = C / 2;
#pragma unroll
  for (int j = 0; j < H; ++j) {
    float send = hi ? v[j] : v[j + H];
    float keep = hi ? v[j + H] : v[j];
    v[j] = keep + __shfl_xor(send, M, 64);
  }
}

// Multi-value butterfly step via DPP quad_perm — masks 1 and 2.
template<int M, int CTRL, int C>
__device__ __forceinline__ void tree_step_dpp(float* v, int lane) {
  const bool hi = (lane & M) != 0;
  const int H = C / 2;
#pragma unroll
  for (int j = 0; j < H; ++j) {
    float send = hi ? v[j] : v[j + H];
    float keep = hi ? v[j + H] : v[j];
    v[j] = keep + dpp_xor<CTRL>(send);
  }
}

// Decode two e4m3 bytes (packed in a ushort) -> float2, via hw converter.
__device__ __forceinline__ f32x2 dec2_fp8(unsigned short t) {
  return __builtin_amdgcn_cvt_pk_f32_fp8((int)(unsigned int)t, false);
}

// fp32 -> e4m3 table conversion via hw converter, 4 values/thread, streaming.
__global__ __launch_bounds__(256) void convert_con(
    const float4* __restrict__ in, unsigned int* __restrict__ out, int n4)
{
  int i = blockIdx.x * 256 + threadIdx.x;
  if (i >= n4) return;
  float4 v = in[i];
  int w = 0;
  w = __builtin_amdgcn_cvt_pk_fp8_f32(v.x * SCALE, v.y * SCALE, w, false);
  w = __builtin_amdgcn_cvt_pk_fp8_f32(v.z * SCALE, v.w * SCALE, w, true);
  out[i] = (unsigned int)w;
}

__global__ __launch_bounds__(256, 8) void skipgram_main(
    const int* __restrict__ centrals,
    const int* __restrict__ pos_ctx,
    const int* __restrict__ neg_ctx,
    const float* __restrict__ word_emb,
    const unsigned short* __restrict__ con8,   // e4m3 table, 64 ushort/row
    float* __restrict__ block_sums)
{
  const int lane = threadIdx.x & 63;
  const int wid = threadIdx.x >> 6;
  const int gw = blockIdx.x * WPB + wid;      // global wave id, 0..8191

  const float2* __restrict__ W = reinterpret_cast<const float2*>(word_emb);

  for (int t = 0; t < NITER; ++t) {
    // Pair index: adjacent for the two iterations (s_load dcache locality).
    int p = gw * NITER + t;
    p = __builtin_amdgcn_readfirstlane(p);    // wave-uniform -> s_load path
    const int b0 = p * BPW;

    // Scalar index loads for both b (wave-uniform addresses -> s_load).
    const int cw0 = centrals[b0],    cw1 = centrals[b0 + 1];
    const int pc0 = pos_ctx[b0],     pc1 = pos_ctx[b0 + 1];
    int ni0[Kn], ni1[Kn];
#pragma unroll
    for (int k = 0; k < Kn; ++k) {
      ni0[k] = neg_ctx[b0 * Kn + k];
      ni1[k] = neg_ctx[(b0 + 1) * Kn + k];
    }

    // Issue all 38 row gathers back-to-back. Full-wave contiguous:
    // word rows 512 B fp32 (float2/lane), con rows 128 B fp8 (ushort/lane).
    const float2 wv0 = W[(size_t)cw0 * 64 + lane];
    const float2 wv1 = W[(size_t)cw1 * 64 + lane];
    const unsigned short cvb0 = con8[(size_t)pc0 * 64 + lane];
    const unsigned short cvb1 = con8[(size_t)pc1 * 64 + lane];
    unsigned short nvb0[Kn], nvb1[Kn];
#pragma unroll
    for (int k = 0; k < Kn; ++k) nvb0[k] = con8[(size_t)ni0[k] * 64 + lane];
#pragma unroll
    for (int k = 0; k < Kn; ++k) nvb1[k] = con8[(size_t)ni1[k] * 64 + lane];

    // Per-lane partial dots for both b (independent chains, ILP).
    float v0[Kn], v1[Kn];
#pragma unroll
    for (int k = 0; k < Kn; ++k) {
      const f32x2 n0 = dec2_fp8(nvb0[k]);
      v0[k] = fmaf(wv0.x, n0.x, wv0.y * n0.y);
      const f32x2 n1 = dec2_fp8(nvb1[k]);
      v1[k] = fmaf(wv1.x, n1.x, wv1.y * n1.y);
    }

    // Butterfly trees: xor-1/xor-2 via DPP (VALU), xor>=4 via shuffle.
    tree_step_dpp<1, XOR1, 16>(v0, lane);  tree_step_dpp<1, XOR1, 16>(v1, lane);
    tree_step_dpp<2, XOR2,  8>(v0, lane);  tree_step_dpp<2, XOR2,  8>(v1, lane);
    tree_step<4, 4>(v0, lane);             tree_step<4, 4>(v1, lane);
    tree_step<8, 2>(v0, lane);             tree_step<8, 2>(v1, lane);
    float s0 = v0[0], s1 = v1[0];
    s0 += __shfl_xor(s0, 16, 64);  s1 += __shfl_xor(s1, 16, 64);
    s0 += __shfl_xor(s0, 32, 64);  s1 += __shfl_xor(s1, 32, 64);
    s0 *= INV_SCALE;               s1 *= INV_SCALE;

    // Sum log-sigmoids of the 16 distinct scores per b.
    float nls0 = log_sigmoid_fast(-s0);
    float nls1 = log_sigmoid_fast(-s1);
    nls0 += dpp_xor<XOR1>(nls0);      nls1 += dpp_xor<XOR1>(nls1);
    nls0 += dpp_xor<XOR2>(nls0);      nls1 += dpp_xor<XOR2>(nls1);
    nls0 += __shfl_xor(nls0, 4, 64);  nls1 += __shfl_xor(nls1, 4, 64);
    nls0 += __shfl_xor(nls0, 8, 64);  nls1 += __shfl_xor(nls1, 8, 64);

    // Positive scores.
    const f32x2 cf0 = dec2_fp8(cvb0);
    const f32x2 cf1 = dec2_fp8(cvb1);
    float pp0 = fmaf(wv0.x, cf0.x, wv0.y * cf0.y);
    float pp1 = fmaf(wv1.x, cf1.x, wv1.y * cf1.y);
    pp0 += dpp_xor<XOR1>(pp0);        pp1 += dpp_xor<XOR1>(pp1);
    pp0 += dpp_xor<XOR2>(pp0);        pp1 += dpp_xor<XOR2>(pp1);
    pp0 += __shfl_xor(pp0,  4, 64);   pp1 += __shfl_xor(pp1,  4, 64);
    pp0 += __shfl_xor(pp0,  8, 64);   pp1 += __shfl_xor(pp1,  8, 64);
    pp0 += __shfl_xor(pp0, 16, 64);   pp1 += __shfl_xor(pp1, 16, 64);
    pp0 += __shfl_xor(pp0, 32, 64);   pp1 += __shfl_xor(pp1, 32, 64);
    pp0 *= INV_SCALE;                 pp1 *= INV_SCALE;

    const float acc = (log_sigmoid_fast(pp0) + nls0)
                    + (log_sigmoid_fast(pp1) + nls1);

    // Per-wave store: no smem, no barrier — waves retire independently.
    if (lane == 0) block_sums[p] = acc;
  }
}

__global__ __launch_bounds__(256) void skipgram_reduce(
    const float* __restrict__ block_sums, float* __restrict__ out)
{
  float s = 0.0f;
#pragma unroll
  for (int i = 0; i < NSUM / 256; ++i) s += block_sums[i * 256 + threadIdx.x];
  s += __shfl_xor(s,  1, 64);
  s += __shfl_xor(s,  2, 64);
  s += __shfl_xor(s,  4, 64);
  s += __shfl_xor(s,  8, 64);
  s += __shfl_xor(s, 16, 64);
  s += __shfl_xor(s, 32, 64);
  __shared__ float smem[4];
  const int lane = threadIdx.x & 63;
  if (lane == 0) smem[threadIdx.x >> 6] = s;
  __syncthreads();
  if (threadIdx.x == 0) {
    float t = (smem[0] + smem[1]) + (smem[2] + smem[3]);
    out[0] = -t * (1.0f / (float)Bn);     // loss = -mean(pos_loss + neg_loss)
  }
}

extern "C" void kernel_launch(void* const* d_in, const int* in_sizes, int n_in,
                              void* d_out, int out_size, void* d_ws, size_t ws_size,
                              hipStream_t stream) {
  const int*   centrals = (const int*)d_in[0];
  const int*   pos_ctx  = (const int*)d_in[1];
  const int*   neg_ctx  = (const int*)d_in[2];
  const float* word_emb = (const float*)d_in[3];
  const float* con_emb  = (const float*)d_in[4];
  float*       out      = (float*)d_out;

  float*        block_sums = (float*)d_ws;                     // 64 KB
  unsigned int* con_fp8 = (unsigned int*)((char*)d_ws + CONV_OFF); // 12.8 MB

  // 1) fp32 -> e4m3 conversion (streaming, 64 MB traffic, hw cvt).
  const int n4 = VOCAB * DIM / 4;                              // 3.2M float4
  convert_con<<<(n4 + 255) / 256, 256, 0, stream>>>(
      (const float4*)con_emb, con_fp8, n4);

  // 2) gathers + dots + log-sigmoid -> per-wave partials (persistent grid).
  skipgram_main<<<NBLK, 256, 0, stream>>>(centrals, pos_ctx, neg_ctx,
                                          word_emb,
                                          (const unsigned short*)con_fp8,
                                          block_sums);

  // 3) final mean.
  skipgram_reduce<<<1, 256, 0, stream>>>(block_sums, out);
}